// Round 12
// baseline (89.204 us; speedup 1.0000x reference)
//
#include <hip/hip_runtime.h>

#define BB 8
#define NNODES 1024
#define FIN 64
#define NH 4
#define NC 32
#define HDIM 128          // HIN == HID == 128
#define NEG_INF_F (-1e9f)

#define LOGITS_CNT (BB*NNODES*NNODES*3)   // 25165824
#define HP_OFF LOGITS_CNT

// scratch inside the (not-yet-written) logits region of d_out
#define CP2_OFF  0                        // conv partial (j-quarter 2) f32
#define CP3_OFF  (BB*NNODES*HDIM)         // conv partial (j-quarter 3) f32
#define CP1_OFF  (2*BB*NNODES*HDIM)       // conv partial (j-quarter 1) f32
#define HHTB_OFF (3*BB*NNODES*HDIM)       // hh^T bf16 [B][128][N] (as ushort)
#define WT_OFF   (4*BB*NNODES*HDIM)       // WT bf16 [3][128][256]  (98304 ush)
#define RT_OFF   (WT_OFF + 49152)         // RT bf16 [3][128][128]  (49152 ush)

// workspace layout (float offsets)
#define WS_HH    0                               // reused: online-softmax stats
#define WS_STATM WS_HH                           // [jq][B][N][4] running max (4*32768)
#define WS_STATS (WS_HH + 131072)                // [jq][B][N][4] running sum (4*32768)
#define WS_SSRC  (WS_HH    + BB*NNODES*HDIM)     // [B][N][4]
#define WS_SDSTT (WS_SSRC  + BB*NNODES*NH)       // [B][4][N]
#define WS_M     (WS_SDSTT + BB*NH*NNODES)       // (unused)
#define WS_RSUM  (WS_M     + BB*NNODES*NH)       // (unused)
#define WS_CONV  (WS_RSUM  + BB*NNODES*NH)       // conv partial (j-quarter 0) f32
#define WS_T     (WS_CONV  + BB*NNODES*HDIM)     // TB bf16 + HPB bf16
#define HPB_FOFF (WS_T + 1572864)

typedef float f32x4 __attribute__((ext_vector_type(4)));
typedef short bf16x8 __attribute__((ext_vector_type(8)));

__device__ __forceinline__ float sigmoidf_(float x) { return 1.0f/(1.0f+__expf(-x)); }
__device__ __forceinline__ float tanhf_(float x) {
  float e = __expf(2.0f*x); return 1.0f - 2.0f/(e+1.0f);
}
__device__ __forceinline__ void ld4(const float* p, float* d) {
  float4 v = *(const float4*)p;
  d[0]=v.x; d[1]=v.y; d[2]=v.z; d[3]=v.w;
}
__device__ __forceinline__ ushort f2b(float x) {
  union { float f; unsigned u; } v; v.f = x;
  unsigned r = v.u + 0x7fffu + ((v.u >> 16) & 1u);
  return (ushort)(r >> 16);
}

// ---------------- Kernel PRE: weight transpose ∪ hh+scores (block roles) -----
#define XK_S 68
#define HT2_S 129
__global__ __launch_bounds__(256) void k_pre(
    const float* __restrict__ x, const float* __restrict__ Wk,
    const float* __restrict__ att_src, const float* __restrict__ att_dst,
    const float* __restrict__ W_u, const float* __restrict__ W_r,
    const float* __restrict__ W_c, const float* __restrict__ R_p,
    const float* __restrict__ R_mu, const float* __restrict__ R_sg,
    float* __restrict__ ws, float* __restrict__ out)
{
  __shared__ float sm[FIN*HDIM + 32*XK_S];   // 41.5 KB
  int blk = blockIdx.x, tid = threadIdx.x;
  if (blk < 18) {
    float* tile = sm;                        // [64][129]
    const float* src; ushort* dst; int k0, nk;
    if (blk < 12) {
      int mat = blk >> 2, ch = blk & 3; k0 = ch*64; nk = 256;
      src = (mat==0) ? W_u : (mat==1) ? W_r : W_c;
      dst = (ushort*)(out + WT_OFF) + mat*32768;
    } else {
      int q = blk - 12; int mat = q >> 1, ch = q & 1; k0 = ch*64; nk = 128;
      src = (mat==0) ? R_p : (mat==1) ? R_mu : R_sg;
      dst = (ushort*)(out + RT_OFF) + mat*16384;
    }
    #pragma unroll
    for (int t = 0; t < 8; ++t) {
      int g = tid + t*256;
      int r = g >> 5, c4 = g & 31;
      *(float4*)&tile[r*129 + c4*4] = *(const float4*)&src[(size_t)(k0+r)*HDIM + c4*4];
    }
    __syncthreads();
    int c = tid >> 1, half = tid & 1;
    ushort tmp[32];
    #pragma unroll
    for (int q = 0; q < 32; ++q) tmp[q] = f2b(tile[(half*32+q)*129 + c]);
    size_t base = (size_t)c*nk + k0 + half*32;
    #pragma unroll
    for (int g = 0; g < 4; ++g) {
      uint4 v;
      v.x = (uint)tmp[g*8+0] | ((uint)tmp[g*8+1] << 16);
      v.y = (uint)tmp[g*8+2] | ((uint)tmp[g*8+3] << 16);
      v.z = (uint)tmp[g*8+4] | ((uint)tmp[g*8+5] << 16);
      v.w = (uint)tmp[g*8+6] | ((uint)tmp[g*8+7] << 16);
      *(uint4*)&dst[base + g*8] = v;
    }
    return;
  }
  int blk2 = blk - 18;
  int b = blk2 >> 5;
  int n0 = (blk2 & 31) * 32;
  float* wk_l = sm;                // [64][128]
  float* x_l  = sm + FIN*HDIM;     // [32][XK_S]
  float* hhT  = sm;                // reuse: [32][HT2_S]
  #pragma unroll
  for (int t = 0; t < 8; ++t) {
    int idx = tid + t*256;
    int r = idx >> 5, c4 = idx & 31;
    *(float4*)&wk_l[r*HDIM + c4*4] = *(const float4*)&Wk[r*HDIM + c4*4];
  }
  #pragma unroll
  for (int t = 0; t < 2; ++t) {
    int idx = tid + t*256;
    int r = idx >> 4, c4 = idx & 15;
    *(float4*)&x_l[r*XK_S + c4*4] =
      *(const float4*)&x[((size_t)(b*NNODES)+n0+r)*FIN + c4*4];
  }
  __syncthreads();
  int col = tid & 127;
  int rh = tid >> 7;
  float acc[16];
  #pragma unroll
  for (int rr = 0; rr < 16; ++rr) acc[rr] = 0.f;
  for (int k4 = 0; k4 < 16; ++k4) {
    float w0 = wk_l[(k4*4+0)*HDIM + col];
    float w1 = wk_l[(k4*4+1)*HDIM + col];
    float w2 = wk_l[(k4*4+2)*HDIM + col];
    float w3 = wk_l[(k4*4+3)*HDIM + col];
    #pragma unroll
    for (int rr = 0; rr < 16; ++rr) {
      float4 xv = *(const float4*)&x_l[(rh*16+rr)*XK_S + k4*4];
      acc[rr] = fmaf(xv.x, w0, fmaf(xv.y, w1, fmaf(xv.z, w2, fmaf(xv.w, w3, acc[rr]))));
    }
  }
  {
    float as = att_src[col], ad = att_dst[col];
    float* ssrc  = ws + WS_SSRC;
    float* sdstT = ws + WS_SDSTT;
    int hI = col >> 5;
    #pragma unroll
    for (int rr = 0; rr < 16; ++rr) {
      int n = n0 + rh*16 + rr;
      float ss = acc[rr]*as, sd = acc[rr]*ad;
      #pragma unroll
      for (int m = 16; m >= 1; m >>= 1) {
        ss += __shfl_xor(ss, m, 64);
        sd += __shfl_xor(sd, m, 64);
      }
      if ((col & 31) == 0) {
        ssrc[((size_t)(b*NNODES)+n)*NH + hI] = ss;
        sdstT[(size_t)(b*NH + hI)*NNODES + n] = sd;
      }
    }
  }
  __syncthreads();
  #pragma unroll
  for (int rr = 0; rr < 16; ++rr)
    hhT[(rh*16+rr)*HT2_S + col] = acc[rr];
  __syncthreads();
  {
    ushort* HHTB = (ushort*)(out + HHTB_OFF);
    int c = tid >> 1, half = tid & 1;
    ushort tmp[16];
    #pragma unroll
    for (int q = 0; q < 16; ++q)
      tmp[q] = f2b(hhT[(half*16+q)*HT2_S + c]);
    size_t base = ((size_t)(b*HDIM)+c)*NNODES + n0 + half*16;
    #pragma unroll
    for (int g = 0; g < 2; ++g) {
      uint4 v;
      v.x = (uint)tmp[g*8+0] | ((uint)tmp[g*8+1] << 16);
      v.y = (uint)tmp[g*8+2] | ((uint)tmp[g*8+3] << 16);
      v.z = (uint)tmp[g*8+4] | ((uint)tmp[g*8+5] << 16);
      v.w = (uint)tmp[g*8+6] | ((uint)tmp[g*8+7] << 16);
      *(uint4*)&HHTB[base + g*8] = v;
    }
  }
}

// ---------------- Kernel C: conv via bf16 MFMA + ONLINE softmax --------------
// grid 1024: b = blk&7; rem = blk>>3 (0..127); it = rem>>2; jq = rem&3.
#define HT_S 40
__global__ __launch_bounds__(256) void k_conv_m(
    const float* __restrict__ a,
    float* __restrict__ ws, float* __restrict__ out)
{
  __shared__ ushort hhT_l[128*HT_S];   // 10240 B
  __shared__ float sdst_l[4*32];
  int tid = threadIdx.x;
  int blk = blockIdx.x;
  int b = blk & 7;
  int rem = blk >> 3;
  int it = rem >> 2, jq = rem & 3;
  int i0 = it * 32;
  int j0b = jq * 256;
  int w = tid >> 6, lane = tid & 63;
  int i0w = i0 + (w & 1) * 16;
  int hp2 = (w >> 1) * 2;
  int fr = lane & 15;
  int i = i0w + fr;
  int koff = (lane >> 4) * 8;
  int crow = (lane >> 4) * 4, ccol = lane & 15;
  const ushort* HHTB = (const ushort*)(out + HHTB_OFF);
  const float* sdstT = ws + WS_SDSTT;
  float ssv[4];
  ld4(&ws[WS_SSRC + ((size_t)(b*NNODES)+i)*4], ssv);
  float m_run[2] = {-3.0e38f, -3.0e38f};
  float s_run[2] = {0.f, 0.f};
  f32x4 acc[2][2];
  #pragma unroll
  for (int h = 0; h < 2; ++h)
    #pragma unroll
    for (int cf = 0; cf < 2; ++cf) acc[h][cf] = (f32x4)0.f;
  const float* arow = a + ((size_t)(b*NNODES)+i)*NNODES;
  for (int ch = 0; ch < 8; ++ch) {
    int j0 = j0b + ch*32;
    #pragma unroll
    for (int s = 0; s < 2; ++s) {
      int seg = tid + s*256;
      int c = seg >> 2, q = seg & 3;
      *(uint4*)&hhT_l[c*HT_S + q*8] =
        *(const uint4*)&HHTB[((size_t)(b*HDIM)+c)*NNODES + j0 + q*8];
    }
    if (tid < 32) {
      int h = tid >> 3, q = tid & 7;
      *(float4*)&sdst_l[h*32 + q*4] =
        *(const float4*)&sdstT[(size_t)(b*NH + h)*NNODES + j0 + q*4];
    }
    float av[8];
    {
      float4 a0 = *(const float4*)&arow[j0 + koff];
      float4 a1 = *(const float4*)&arow[j0 + koff + 4];
      av[0]=a0.x; av[1]=a0.y; av[2]=a0.z; av[3]=a0.w;
      av[4]=a1.x; av[5]=a1.y; av[6]=a1.z; av[7]=a1.w;
    }
    __syncthreads();
    float am[8];
    #pragma unroll
    for (int t = 0; t < 8; ++t) am[t] = fmaf(av[t], 1e9f, -1e9f);
    #pragma unroll
    for (int h2 = 0; h2 < 2; ++h2) {
      int hh_ = hp2 + h2;
      float sd[8];
      ld4(&sdst_l[hh_*32 + koff], sd);
      ld4(&sdst_l[hh_*32 + koff + 4], sd + 4);
      float e[8];
      float mx = -3.0e38f;
      #pragma unroll
      for (int t = 0; t < 8; ++t) {
        float s = ssv[hh_] + sd[t];
        s = fmaxf(s, 0.2f*s);
        e[t] = s + am[t];
        mx = fmaxf(mx, e[t]);
      }
      mx = fmaxf(mx, __shfl_xor(mx, 16, 64));
      mx = fmaxf(mx, __shfl_xor(mx, 32, 64));
      float mnew = fmaxf(m_run[h2], mx);
      float scale = __expf(m_run[h2] - mnew);
      bf16x8 pf;
      float sum8 = 0.f;
      #pragma unroll
      for (int t = 0; t < 8; ++t) {
        float p = __expf(e[t] - mnew);
        sum8 += p;
        pf[t] = (short)f2b(p);
      }
      sum8 += __shfl_xor(sum8, 16, 64);
      sum8 += __shfl_xor(sum8, 32, 64);
      s_run[h2] = s_run[h2]*scale + sum8;
      m_run[h2] = mnew;
      float sc[4];
      #pragma unroll
      for (int r = 0; r < 4; ++r) sc[r] = __shfl(scale, crow + r, 64);
      #pragma unroll
      for (int cf = 0; cf < 2; ++cf) {
        #pragma unroll
        for (int r = 0; r < 4; ++r) acc[h2][cf][r] *= sc[r];
        int c = hh_*32 + cf*16 + fr;
        bf16x8 bfr = *(const bf16x8*)&hhT_l[c*HT_S + koff];
        acc[h2][cf] = __builtin_amdgcn_mfma_f32_16x16x32_bf16(
            pf, bfr, acc[h2][cf], 0, 0, 0);
      }
    }
    __syncthreads();
  }
  float* cp = (jq == 0) ? (ws + WS_CONV) : (jq == 1) ? (out + CP1_OFF)
            : (jq == 2) ? (out + CP2_OFF) : (out + CP3_OFF);
  #pragma unroll
  for (int h2 = 0; h2 < 2; ++h2)
    #pragma unroll
    for (int cf = 0; cf < 2; ++cf)
      #pragma unroll
      for (int r = 0; r < 4; ++r)
        cp[((size_t)(b*NNODES) + i0w + crow + r)*HDIM + (hp2+h2)*32 + cf*16 + ccol]
          = acc[h2][cf][r];
  if (lane < 16) {
    size_t si = ((size_t)(b*NNODES) + i0w + lane)*NH;
    ws[WS_STATM + jq*32768 + si + hp2]     = m_run[0];
    ws[WS_STATM + jq*32768 + si + hp2 + 1] = m_run[1];
    ws[WS_STATS + jq*32768 + si + hp2]     = s_run[0];
    ws[WS_STATS + jq*32768 + si + hp2 + 1] = s_run[1];
  }
}

// ---------------- Kernel D: merge(4) + GRU gates + h' + T (bf16 MFMA) --------
#define CU_S 264   // bf16 stride
#define RH_S 136
__global__ __launch_bounds__(256) void k_fuse(
    const float* __restrict__ h_in,
    const float* __restrict__ b_u, const float* __restrict__ b_r,
    const float* __restrict__ b_c, const float* __restrict__ bias_gat,
    float* __restrict__ ws, float* __restrict__ out)
{
  __shared__ ushort cu_l[16*CU_S];
  __shared__ ushort rh_l[16*RH_S];
  __shared__ ushort hp_l[16*RH_S];
  int tid = threadIdx.x;
  int blk = blockIdx.x;
  int b = blk & 7;
  int n0 = (blk >> 3) * 16;
  const float* cp0 = ws + WS_CONV;
  const float* cp1 = out + CP1_OFF;
  const float* cp2 = out + CP2_OFF;
  const float* cp3 = out + CP3_OFF;
  const ushort* WT = (const ushort*)(out + WT_OFF);
  const ushort* RT = (const ushort*)(out + RT_OFF);
  ushort* HPB = (ushort*)(ws + HPB_FOFF);
  ushort* TB  = (ushort*)(ws + WS_T);
  #pragma unroll
  for (int t = 0; t < 4; ++t) {
    int g = tid + t*256;
    int row = g >> 6, c4 = g & 63;
    float v[4];
    if (c4 < 32) {
      int hh_ = c4 >> 3;
      size_t sidx = ((size_t)(b*NNODES)+n0+row)*NH + hh_;
      float m0 = ws[WS_STATM + sidx],         m1 = ws[WS_STATM + 32768 + sidx];
      float m2 = ws[WS_STATM + 65536 + sidx], m3 = ws[WS_STATM + 98304 + sidx];
      float s0 = ws[WS_STATS + sidx],         s1 = ws[WS_STATS + 32768 + sidx];
      float s2 = ws[WS_STATS + 65536 + sidx], s3 = ws[WS_STATS + 98304 + sidx];
      float M = fmaxf(fmaxf(m0, m1), fmaxf(m2, m3));
      float f0 = __expf(m0 - M), f1 = __expf(m1 - M);
      float f2 = __expf(m2 - M), f3 = __expf(m3 - M);
      float rd = 1.0f / (s0*f0 + s1*f1 + s2*f2 + s3*f3);
      f0 *= rd; f1 *= rd; f2 *= rd; f3 *= rd;
      size_t cbase = ((size_t)(b*NNODES)+n0+row)*HDIM + c4*4;
      float4 v0 = *(const float4*)&cp0[cbase];
      float4 v1 = *(const float4*)&cp1[cbase];
      float4 v2 = *(const float4*)&cp2[cbase];
      float4 v3 = *(const float4*)&cp3[cbase];
      float4 bv = *(const float4*)&bias_gat[c4*4];
      v[0] = v0.x*f0 + v1.x*f1 + v2.x*f2 + v3.x*f3 + bv.x;
      v[1] = v0.y*f0 + v1.y*f1 + v2.y*f2 + v3.y*f3 + bv.y;
      v[2] = v0.z*f0 + v1.z*f1 + v2.z*f2 + v3.z*f3 + bv.z;
      v[3] = v0.w*f0 + v1.w*f1 + v2.w*f2 + v3.w*f3 + bv.w;
    } else {
      ld4(&h_in[((size_t)(b*NNODES)+n0+row)*HDIM + (c4-32)*4], v);
    }
    ushort4 o; o.x=f2b(v[0]); o.y=f2b(v[1]); o.z=f2b(v[2]); o.w=f2b(v[3]);
    *(ushort4*)&cu_l[row*CU_S + c4*4] = o;
  }
  __syncthreads();
  int w = tid >> 6, lane = tid & 63;
  int wn = w * 32;
  int fr = lane & 15, k8 = (lane >> 4) * 8;
  int crow = (lane >> 4) * 4, ccol = lane & 15;
  f32x4 acc_u[2], acc_r[2];
  acc_u[0]=(f32x4)0.f; acc_u[1]=(f32x4)0.f; acc_r[0]=(f32x4)0.f; acc_r[1]=(f32x4)0.f;
  #pragma unroll
  for (int ks = 0; ks < 8; ++ks) {
    bf16x8 afr = *(const bf16x8*)&cu_l[fr*CU_S + ks*32 + k8];
    #pragma unroll
    for (int nn = 0; nn < 2; ++nn) {
      int row = wn + nn*16 + fr;
      bf16x8 bu_ = *(const bf16x8*)&WT[(size_t)row*256 + ks*32 + k8];
      bf16x8 br_ = *(const bf16x8*)&WT[32768 + (size_t)row*256 + ks*32 + k8];
      acc_u[nn] = __builtin_amdgcn_mfma_f32_16x16x32_bf16(afr, bu_, acc_u[nn], 0,0,0);
      acc_r[nn] = __builtin_amdgcn_mfma_f32_16x16x32_bf16(afr, br_, acc_r[nn], 0,0,0);
    }
  }
  float u_reg[2][4], hv[2][4];
  float bu4[4], br4[4], bc4[4];
  #pragma unroll
  for (int r = 0; r < 4; ++r) {
    bu4[r] = b_u[n0 + crow + r];
    br4[r] = b_r[n0 + crow + r];
    bc4[r] = b_c[n0 + crow + r];
  }
  #pragma unroll
  for (int nn = 0; nn < 2; ++nn) {
    int col = wn + nn*16 + ccol;
    #pragma unroll
    for (int r = 0; r < 4; ++r) {
      int rown = crow + r;
      float h_ = h_in[((size_t)(b*NNODES)+n0+rown)*HDIM + col];
      hv[nn][r] = h_;
      u_reg[nn][r] = sigmoidf_(bu4[r] + acc_u[nn][r]);
      float rr_ = sigmoidf_(br4[r] + acc_r[nn][r]);
      rh_l[rown*RH_S + col] = f2b(rr_ * h_);
    }
  }
  __syncthreads();
  f32x4 acc_c[2];
  acc_c[0]=(f32x4)0.f; acc_c[1]=(f32x4)0.f;
  #pragma unroll
  for (int ks = 0; ks < 8; ++ks) {
    bf16x8 afr = (ks < 4)
      ? *(const bf16x8*)&cu_l[fr*CU_S + ks*32 + k8]
      : *(const bf16x8*)&rh_l[fr*RH_S + (ks-4)*32 + k8];
    #pragma unroll
    for (int nn = 0; nn < 2; ++nn) {
      int row = wn + nn*16 + fr;
      bf16x8 bc_ = *(const bf16x8*)&WT[65536 + (size_t)row*256 + ks*32 + k8];
      acc_c[nn] = __builtin_amdgcn_mfma_f32_16x16x32_bf16(afr, bc_, acc_c[nn], 0,0,0);
    }
  }
  #pragma unroll
  for (int nn = 0; nn < 2; ++nn) {
    int col = wn + nn*16 + ccol;
    #pragma unroll
    for (int r = 0; r < 4; ++r) {
      int rown = crow + r;
      float cc = tanhf_(bc4[r] + acc_c[nn][r]);
      float u_ = u_reg[nn][r];
      float hp = u_*hv[nn][r] + (1.0f-u_)*cc;
      out[HP_OFF + ((size_t)(b*NNODES)+n0+rown)*HDIM + col] = hp;
      ushort hb = f2b(hp);
      HPB[((size_t)(b*NNODES)+n0+rown)*HDIM + col] = hb;
      hp_l[rown*RH_S + col] = hb;
    }
  }
  __syncthreads();
  #pragma unroll
  for (int k3 = 0; k3 < 3; ++k3) {
    f32x4 acc_t[2];
    acc_t[0]=(f32x4)0.f; acc_t[1]=(f32x4)0.f;
    #pragma unroll
    for (int ks = 0; ks < 4; ++ks) {
      bf16x8 afr = *(const bf16x8*)&hp_l[fr*RH_S + ks*32 + k8];
      #pragma unroll
      for (int nn = 0; nn < 2; ++nn) {
        int row = wn + nn*16 + fr;
        bf16x8 bfr = *(const bf16x8*)&RT[k3*16384 + (size_t)row*128 + ks*32 + k8];
        acc_t[nn] = __builtin_amdgcn_mfma_f32_16x16x32_bf16(afr, bfr, acc_t[nn], 0,0,0);
      }
    }
    #pragma unroll
    for (int nn = 0; nn < 2; ++nn) {
      int col = wn + nn*16 + ccol;
      #pragma unroll
      for (int r = 0; r < 4; ++r)
        TB[((size_t)((b*3+k3)*NNODES)+n0+crow+r)*HDIM + col] = f2b(acc_t[nn][r]);
    }
  }
}

// ---------------- Kernel F: logits — hp in regs, one T panel staged/k3 -------
#define LT_S 136
__global__ __launch_bounds__(256) void k_logits_m(
    const float* __restrict__ ws, float* __restrict__ out)
{
  __shared__ ushort t_b[64*LT_S];   // 17.4 KB
  const ushort* TB  = (const ushort*)(ws + WS_T);
  const ushort* HPB = (const ushort*)(ws + HPB_FOFF);
  int tid = threadIdx.x;
  int blk = blockIdx.x;
  int b = blk & 7;
  int rem = blk >> 3;
  int nt = rem >> 4, mt = rem & 15;
  int n0 = nt*64, m0 = mt*64;
  int w = tid >> 6, lane = tid & 63;
  int nbase = (w >> 1) * 32, mbase = (w & 1) * 32;
  int frow = lane & 15, fk = (lane >> 4) * 8;
  // hp B-fragments: k3-invariant, load once into registers (bulk, coalesced)
  bf16x8 bfr[4][2];
  #pragma unroll
  for (int ks = 0; ks < 4; ++ks)
    #pragma unroll
    for (int mm = 0; mm < 2; ++mm)
      bfr[ks][mm] = *(const bf16x8*)&HPB[
        ((size_t)(b*NNODES) + m0 + mbase + mm*16 + frow)*HDIM + ks*32 + fk];
  f32x4 acc[3][2][2];
  #pragma unroll
  for (int k3 = 0; k3 < 3; ++k3)
    #pragma unroll
    for (int nn = 0; nn < 2; ++nn)
      #pragma unroll
      for (int mm = 0; mm < 2; ++mm) acc[k3][nn][mm] = (f32x4)0.f;
  for (int k3 = 0; k3 < 3; ++k3) {
    if (k3) __syncthreads();     // protect t_b reuse
    #pragma unroll
    for (int t = 0; t < 4; ++t) {
      int idx = tid + t*256;
      int r = idx >> 4, c = idx & 15;
      *(uint4*)&t_b[r*LT_S + c*8] =
        *(const uint4*)&TB[((size_t)((b*3+k3)*NNODES)+n0+r)*HDIM + c*8];
    }
    __syncthreads();
    #pragma unroll
    for (int ks = 0; ks < 4; ++ks) {
      int ko = ks*32 + fk;
      #pragma unroll
      for (int nn = 0; nn < 2; ++nn) {
        bf16x8 afr = *(const bf16x8*)&t_b[(nbase + nn*16 + frow)*LT_S + ko];
        #pragma unroll
        for (int mm = 0; mm < 2; ++mm)
          acc[k3][nn][mm] = __builtin_amdgcn_mfma_f32_16x16x32_bf16(
              afr, bfr[ks][mm], acc[k3][nn][mm], 0, 0, 0);
      }
    }
  }
  int crow = (lane >> 4) * 4, ccol = lane & 15;
  #pragma unroll
  for (int nn = 0; nn < 2; ++nn)
    #pragma unroll
    for (int mm = 0; mm < 2; ++mm)
      #pragma unroll
      for (int r = 0; r < 4; ++r) {
        int n = n0 + nbase + nn*16 + crow + r;
        int m = m0 + mbase + mm*16 + ccol;
        float* po = &out[(((size_t)(b*NNODES) + n)*NNODES + m)*3];
        po[0] = acc[0][nn][mm][r];
        po[1] = acc[1][nn][mm][r];
        po[2] = acc[2][nn][mm][r];
      }
}

extern "C" void kernel_launch(void* const* d_in, const int* in_sizes, int n_in,
                              void* d_out, int out_size, void* d_ws, size_t ws_size,
                              hipStream_t stream) {
  (void)in_sizes; (void)n_in; (void)out_size; (void)ws_size;
  const float* x        = (const float*)d_in[0];
  const float* a        = (const float*)d_in[1];
  const float* h        = (const float*)d_in[2];
  const float* Wk       = (const float*)d_in[3];
  const float* att_src  = (const float*)d_in[4];
  const float* att_dst  = (const float*)d_in[5];
  const float* bias_gat = (const float*)d_in[6];
  const float* b_u      = (const float*)d_in[7];
  const float* b_r      = (const float*)d_in[8];
  const float* b_c      = (const float*)d_in[9];
  const float* W_u      = (const float*)d_in[10];
  const float* W_r      = (const float*)d_in[11];
  const float* W_c      = (const float*)d_in[12];
  const float* R_p      = (const float*)d_in[13];
  const float* R_mu     = (const float*)d_in[14];
  const float* R_sg     = (const float*)d_in[15];
  float* out = (float*)d_out;
  float* ws  = (float*)d_ws;

  hipLaunchKernelGGL(k_pre, dim3(274), dim3(256), 0, stream,
                     x, Wk, att_src, att_dst, W_u, W_r, W_c, R_p, R_mu, R_sg, ws, out);
  hipLaunchKernelGGL(k_conv_m, dim3(1024), dim3(256), 0, stream, a, ws, out);
  hipLaunchKernelGGL(k_fuse, dim3(512), dim3(256), 0, stream,
                     h, b_u, b_r, b_c, bias_gat, ws, out);
  hipLaunchKernelGGL(k_logits_m, dim3(2048), dim3(256), 0, stream, ws, out);
}

// Round 13
// 85.985 us; speedup vs baseline: 1.0374x; 1.0374x over previous
//
#include <hip/hip_runtime.h>

#define BB 8
#define NNODES 1024
#define FIN 64
#define NH 4
#define NC 32
#define HDIM 128          // HIN == HID == 128
#define NEG_INF_F (-1e9f)

#define LOGITS_CNT (BB*NNODES*NNODES*3)   // 25165824
#define HP_OFF LOGITS_CNT

// scratch inside the (not-yet-written) logits region of d_out
#define CP2_OFF  0                        // conv partial (j-quarter 2) f32
#define CP3_OFF  (BB*NNODES*HDIM)         // conv partial (j-quarter 3) f32
#define CP1_OFF  (2*BB*NNODES*HDIM)       // conv partial (j-quarter 1) f32
#define HHTB_OFF (3*BB*NNODES*HDIM)       // hh^T bf16 [B][128][N] (as ushort)
#define WT_OFF   (4*BB*NNODES*HDIM)       // WT bf16 [3][128][256]  (98304 ush)
#define RT_OFF   (WT_OFF + 49152)         // RT bf16 [3][128][128]  (49152 ush)

// workspace layout (float offsets)
#define WS_HH    0                               // reused: online-softmax stats
#define WS_STATM WS_HH                           // [jq][B][N][4] running max (4*32768)
#define WS_STATS (WS_HH + 131072)                // [jq][B][N][4] running sum (4*32768)
#define WS_SSRC  (WS_HH    + BB*NNODES*HDIM)     // [B][N][4]
#define WS_SDSTT (WS_SSRC  + BB*NNODES*NH)       // [B][4][N]
#define WS_M     (WS_SDSTT + BB*NH*NNODES)       // (unused)
#define WS_RSUM  (WS_M     + BB*NNODES*NH)       // (unused)
#define WS_CONV  (WS_RSUM  + BB*NNODES*NH)       // conv partial (j-quarter 0) f32
#define WS_T     (WS_CONV  + BB*NNODES*HDIM)     // TB bf16 + HPB bf16
#define HPB_FOFF (WS_T + 1572864)

typedef float f32x4 __attribute__((ext_vector_type(4)));
typedef short bf16x8 __attribute__((ext_vector_type(8)));

__device__ __forceinline__ float sigmoidf_(float x) { return 1.0f/(1.0f+__expf(-x)); }
__device__ __forceinline__ float tanhf_(float x) {
  float e = __expf(2.0f*x); return 1.0f - 2.0f/(e+1.0f);
}
__device__ __forceinline__ void ld4(const float* p, float* d) {
  float4 v = *(const float4*)p;
  d[0]=v.x; d[1]=v.y; d[2]=v.z; d[3]=v.w;
}
__device__ __forceinline__ ushort f2b(float x) {
  union { float f; unsigned u; } v; v.f = x;
  unsigned r = v.u + 0x7fffu + ((v.u >> 16) & 1u);
  return (ushort)(r >> 16);
}

// ---------------- Kernel PRE: weight transpose ∪ hh+scores (block roles) -----
#define XK_S 68
#define HT2_S 129
__global__ __launch_bounds__(256) void k_pre(
    const float* __restrict__ x, const float* __restrict__ Wk,
    const float* __restrict__ att_src, const float* __restrict__ att_dst,
    const float* __restrict__ W_u, const float* __restrict__ W_r,
    const float* __restrict__ W_c, const float* __restrict__ R_p,
    const float* __restrict__ R_mu, const float* __restrict__ R_sg,
    float* __restrict__ ws, float* __restrict__ out)
{
  __shared__ float sm[FIN*HDIM + 32*XK_S];   // 41.5 KB
  int blk = blockIdx.x, tid = threadIdx.x;
  if (blk < 18) {
    float* tile = sm;                        // [64][129]
    const float* src; ushort* dst; int k0, nk;
    if (blk < 12) {
      int mat = blk >> 2, ch = blk & 3; k0 = ch*64; nk = 256;
      src = (mat==0) ? W_u : (mat==1) ? W_r : W_c;
      dst = (ushort*)(out + WT_OFF) + mat*32768;
    } else {
      int q = blk - 12; int mat = q >> 1, ch = q & 1; k0 = ch*64; nk = 128;
      src = (mat==0) ? R_p : (mat==1) ? R_mu : R_sg;
      dst = (ushort*)(out + RT_OFF) + mat*16384;
    }
    #pragma unroll
    for (int t = 0; t < 8; ++t) {
      int g = tid + t*256;
      int r = g >> 5, c4 = g & 31;
      *(float4*)&tile[r*129 + c4*4] = *(const float4*)&src[(size_t)(k0+r)*HDIM + c4*4];
    }
    __syncthreads();
    int c = tid >> 1, half = tid & 1;
    ushort tmp[32];
    #pragma unroll
    for (int q = 0; q < 32; ++q) tmp[q] = f2b(tile[(half*32+q)*129 + c]);
    size_t base = (size_t)c*nk + k0 + half*32;
    #pragma unroll
    for (int g = 0; g < 4; ++g) {
      uint4 v;
      v.x = (uint)tmp[g*8+0] | ((uint)tmp[g*8+1] << 16);
      v.y = (uint)tmp[g*8+2] | ((uint)tmp[g*8+3] << 16);
      v.z = (uint)tmp[g*8+4] | ((uint)tmp[g*8+5] << 16);
      v.w = (uint)tmp[g*8+6] | ((uint)tmp[g*8+7] << 16);
      *(uint4*)&dst[base + g*8] = v;
    }
    return;
  }
  int blk2 = blk - 18;
  int b = blk2 >> 5;
  int n0 = (blk2 & 31) * 32;
  float* wk_l = sm;                // [64][128]
  float* x_l  = sm + FIN*HDIM;     // [32][XK_S]
  float* hhT  = sm;                // reuse: [32][HT2_S]
  #pragma unroll
  for (int t = 0; t < 8; ++t) {
    int idx = tid + t*256;
    int r = idx >> 5, c4 = idx & 31;
    *(float4*)&wk_l[r*HDIM + c4*4] = *(const float4*)&Wk[r*HDIM + c4*4];
  }
  #pragma unroll
  for (int t = 0; t < 2; ++t) {
    int idx = tid + t*256;
    int r = idx >> 4, c4 = idx & 15;
    *(float4*)&x_l[r*XK_S + c4*4] =
      *(const float4*)&x[((size_t)(b*NNODES)+n0+r)*FIN + c4*4];
  }
  __syncthreads();
  int col = tid & 127;
  int rh = tid >> 7;
  float acc[16];
  #pragma unroll
  for (int rr = 0; rr < 16; ++rr) acc[rr] = 0.f;
  for (int k4 = 0; k4 < 16; ++k4) {
    float w0 = wk_l[(k4*4+0)*HDIM + col];
    float w1 = wk_l[(k4*4+1)*HDIM + col];
    float w2 = wk_l[(k4*4+2)*HDIM + col];
    float w3 = wk_l[(k4*4+3)*HDIM + col];
    #pragma unroll
    for (int rr = 0; rr < 16; ++rr) {
      float4 xv = *(const float4*)&x_l[(rh*16+rr)*XK_S + k4*4];
      acc[rr] = fmaf(xv.x, w0, fmaf(xv.y, w1, fmaf(xv.z, w2, fmaf(xv.w, w3, acc[rr]))));
    }
  }
  {
    float as = att_src[col], ad = att_dst[col];
    float* ssrc  = ws + WS_SSRC;
    float* sdstT = ws + WS_SDSTT;
    int hI = col >> 5;
    #pragma unroll
    for (int rr = 0; rr < 16; ++rr) {
      int n = n0 + rh*16 + rr;
      float ss = acc[rr]*as, sd = acc[rr]*ad;
      #pragma unroll
      for (int m = 16; m >= 1; m >>= 1) {
        ss += __shfl_xor(ss, m, 64);
        sd += __shfl_xor(sd, m, 64);
      }
      if ((col & 31) == 0) {
        ssrc[((size_t)(b*NNODES)+n)*NH + hI] = ss;
        sdstT[(size_t)(b*NH + hI)*NNODES + n] = sd;
      }
    }
  }
  __syncthreads();
  #pragma unroll
  for (int rr = 0; rr < 16; ++rr)
    hhT[(rh*16+rr)*HT2_S + col] = acc[rr];
  __syncthreads();
  {
    ushort* HHTB = (ushort*)(out + HHTB_OFF);
    int c = tid >> 1, half = tid & 1;
    ushort tmp[16];
    #pragma unroll
    for (int q = 0; q < 16; ++q)
      tmp[q] = f2b(hhT[(half*16+q)*HT2_S + c]);
    size_t base = ((size_t)(b*HDIM)+c)*NNODES + n0 + half*16;
    #pragma unroll
    for (int g = 0; g < 2; ++g) {
      uint4 v;
      v.x = (uint)tmp[g*8+0] | ((uint)tmp[g*8+1] << 16);
      v.y = (uint)tmp[g*8+2] | ((uint)tmp[g*8+3] << 16);
      v.z = (uint)tmp[g*8+4] | ((uint)tmp[g*8+5] << 16);
      v.w = (uint)tmp[g*8+6] | ((uint)tmp[g*8+7] << 16);
      *(uint4*)&HHTB[base + g*8] = v;
    }
  }
}

// ---------------- Kernel C: conv via bf16 MFMA + ONLINE softmax --------------
// grid 1024: b = blk&7; rem = blk>>3 (0..127); it = rem>>2; jq = rem&3.
#define HT_S 40
__global__ __launch_bounds__(256) void k_conv_m(
    const float* __restrict__ a,
    float* __restrict__ ws, float* __restrict__ out)
{
  __shared__ ushort hhT_l[128*HT_S];   // 10240 B
  __shared__ float sdst_l[4*32];
  int tid = threadIdx.x;
  int blk = blockIdx.x;
  int b = blk & 7;
  int rem = blk >> 3;
  int it = rem >> 2, jq = rem & 3;
  int i0 = it * 32;
  int j0b = jq * 256;
  int w = tid >> 6, lane = tid & 63;
  int i0w = i0 + (w & 1) * 16;
  int hp2 = (w >> 1) * 2;
  int fr = lane & 15;
  int i = i0w + fr;
  int koff = (lane >> 4) * 8;
  int crow = (lane >> 4) * 4, ccol = lane & 15;
  const ushort* HHTB = (const ushort*)(out + HHTB_OFF);
  const float* sdstT = ws + WS_SDSTT;
  float ssv[4];
  ld4(&ws[WS_SSRC + ((size_t)(b*NNODES)+i)*4], ssv);
  float m_run[2] = {-3.0e38f, -3.0e38f};
  float s_run[2] = {0.f, 0.f};
  f32x4 acc[2][2];
  #pragma unroll
  for (int h = 0; h < 2; ++h)
    #pragma unroll
    for (int cf = 0; cf < 2; ++cf) acc[h][cf] = (f32x4)0.f;
  const float* arow = a + ((size_t)(b*NNODES)+i)*NNODES;
  for (int ch = 0; ch < 8; ++ch) {
    int j0 = j0b + ch*32;
    #pragma unroll
    for (int s = 0; s < 2; ++s) {
      int seg = tid + s*256;
      int c = seg >> 2, q = seg & 3;
      *(uint4*)&hhT_l[c*HT_S + q*8] =
        *(const uint4*)&HHTB[((size_t)(b*HDIM)+c)*NNODES + j0 + q*8];
    }
    if (tid < 32) {
      int h = tid >> 3, q = tid & 7;
      *(float4*)&sdst_l[h*32 + q*4] =
        *(const float4*)&sdstT[(size_t)(b*NH + h)*NNODES + j0 + q*4];
    }
    float av[8];
    {
      float4 a0 = *(const float4*)&arow[j0 + koff];
      float4 a1 = *(const float4*)&arow[j0 + koff + 4];
      av[0]=a0.x; av[1]=a0.y; av[2]=a0.z; av[3]=a0.w;
      av[4]=a1.x; av[5]=a1.y; av[6]=a1.z; av[7]=a1.w;
    }
    __syncthreads();
    float am[8];
    #pragma unroll
    for (int t = 0; t < 8; ++t) am[t] = fmaf(av[t], 1e9f, -1e9f);
    #pragma unroll
    for (int h2 = 0; h2 < 2; ++h2) {
      int hh_ = hp2 + h2;
      float sd[8];
      ld4(&sdst_l[hh_*32 + koff], sd);
      ld4(&sdst_l[hh_*32 + koff + 4], sd + 4);
      float e[8];
      float mx = -3.0e38f;
      #pragma unroll
      for (int t = 0; t < 8; ++t) {
        float s = ssv[hh_] + sd[t];
        s = fmaxf(s, 0.2f*s);
        e[t] = s + am[t];
        mx = fmaxf(mx, e[t]);
      }
      mx = fmaxf(mx, __shfl_xor(mx, 16, 64));
      mx = fmaxf(mx, __shfl_xor(mx, 32, 64));
      float mnew = fmaxf(m_run[h2], mx);
      float scale = __expf(m_run[h2] - mnew);
      bf16x8 pf;
      float sum8 = 0.f;
      #pragma unroll
      for (int t = 0; t < 8; ++t) {
        float p = __expf(e[t] - mnew);
        sum8 += p;
        pf[t] = (short)f2b(p);
      }
      sum8 += __shfl_xor(sum8, 16, 64);
      sum8 += __shfl_xor(sum8, 32, 64);
      s_run[h2] = s_run[h2]*scale + sum8;
      m_run[h2] = mnew;
      float sc[4];
      #pragma unroll
      for (int r = 0; r < 4; ++r) sc[r] = __shfl(scale, crow + r, 64);
      #pragma unroll
      for (int cf = 0; cf < 2; ++cf) {
        #pragma unroll
        for (int r = 0; r < 4; ++r) acc[h2][cf][r] *= sc[r];
        int c = hh_*32 + cf*16 + fr;
        bf16x8 bfr = *(const bf16x8*)&hhT_l[c*HT_S + koff];
        acc[h2][cf] = __builtin_amdgcn_mfma_f32_16x16x32_bf16(
            pf, bfr, acc[h2][cf], 0, 0, 0);
      }
    }
    __syncthreads();
  }
  float* cp = (jq == 0) ? (ws + WS_CONV) : (jq == 1) ? (out + CP1_OFF)
            : (jq == 2) ? (out + CP2_OFF) : (out + CP3_OFF);
  #pragma unroll
  for (int h2 = 0; h2 < 2; ++h2)
    #pragma unroll
    for (int cf = 0; cf < 2; ++cf)
      #pragma unroll
      for (int r = 0; r < 4; ++r)
        cp[((size_t)(b*NNODES) + i0w + crow + r)*HDIM + (hp2+h2)*32 + cf*16 + ccol]
          = acc[h2][cf][r];
  if (lane < 16) {
    size_t si = ((size_t)(b*NNODES) + i0w + lane)*NH;
    ws[WS_STATM + jq*32768 + si + hp2]     = m_run[0];
    ws[WS_STATM + jq*32768 + si + hp2 + 1] = m_run[1];
    ws[WS_STATS + jq*32768 + si + hp2]     = s_run[0];
    ws[WS_STATS + jq*32768 + si + hp2 + 1] = s_run[1];
  }
}

// ---------------- Kernel D: merge(4) + GRU gates + h' + T (bf16 MFMA) --------
#define CU_S 264   // bf16 stride
#define RH_S 136
__global__ __launch_bounds__(256) void k_fuse(
    const float* __restrict__ h_in,
    const float* __restrict__ b_u, const float* __restrict__ b_r,
    const float* __restrict__ b_c, const float* __restrict__ bias_gat,
    float* __restrict__ ws, float* __restrict__ out)
{
  __shared__ ushort cu_l[16*CU_S];
  __shared__ ushort rh_l[16*RH_S];
  __shared__ ushort hp_l[16*RH_S];
  int tid = threadIdx.x;
  int blk = blockIdx.x;
  int b = blk & 7;
  int n0 = (blk >> 3) * 16;
  const float* cp0 = ws + WS_CONV;
  const float* cp1 = out + CP1_OFF;
  const float* cp2 = out + CP2_OFF;
  const float* cp3 = out + CP3_OFF;
  const ushort* WT = (const ushort*)(out + WT_OFF);
  const ushort* RT = (const ushort*)(out + RT_OFF);
  ushort* HPB = (ushort*)(ws + HPB_FOFF);
  ushort* TB  = (ushort*)(ws + WS_T);
  #pragma unroll
  for (int t = 0; t < 4; ++t) {
    int g = tid + t*256;
    int row = g >> 6, c4 = g & 63;
    float v[4];
    if (c4 < 32) {
      int hh_ = c4 >> 3;
      size_t sidx = ((size_t)(b*NNODES)+n0+row)*NH + hh_;
      float m0 = ws[WS_STATM + sidx],         m1 = ws[WS_STATM + 32768 + sidx];
      float m2 = ws[WS_STATM + 65536 + sidx], m3 = ws[WS_STATM + 98304 + sidx];
      float s0 = ws[WS_STATS + sidx],         s1 = ws[WS_STATS + 32768 + sidx];
      float s2 = ws[WS_STATS + 65536 + sidx], s3 = ws[WS_STATS + 98304 + sidx];
      float M = fmaxf(fmaxf(m0, m1), fmaxf(m2, m3));
      float f0 = __expf(m0 - M), f1 = __expf(m1 - M);
      float f2 = __expf(m2 - M), f3 = __expf(m3 - M);
      float rd = 1.0f / (s0*f0 + s1*f1 + s2*f2 + s3*f3);
      f0 *= rd; f1 *= rd; f2 *= rd; f3 *= rd;
      size_t cbase = ((size_t)(b*NNODES)+n0+row)*HDIM + c4*4;
      float4 v0 = *(const float4*)&cp0[cbase];
      float4 v1 = *(const float4*)&cp1[cbase];
      float4 v2 = *(const float4*)&cp2[cbase];
      float4 v3 = *(const float4*)&cp3[cbase];
      float4 bv = *(const float4*)&bias_gat[c4*4];
      v[0] = v0.x*f0 + v1.x*f1 + v2.x*f2 + v3.x*f3 + bv.x;
      v[1] = v0.y*f0 + v1.y*f1 + v2.y*f2 + v3.y*f3 + bv.y;
      v[2] = v0.z*f0 + v1.z*f1 + v2.z*f2 + v3.z*f3 + bv.z;
      v[3] = v0.w*f0 + v1.w*f1 + v2.w*f2 + v3.w*f3 + bv.w;
    } else {
      ld4(&h_in[((size_t)(b*NNODES)+n0+row)*HDIM + (c4-32)*4], v);
    }
    ushort4 o; o.x=f2b(v[0]); o.y=f2b(v[1]); o.z=f2b(v[2]); o.w=f2b(v[3]);
    *(ushort4*)&cu_l[row*CU_S + c4*4] = o;
  }
  __syncthreads();
  int w = tid >> 6, lane = tid & 63;
  int wn = w * 32;
  int fr = lane & 15, k8 = (lane >> 4) * 8;
  int crow = (lane >> 4) * 4, ccol = lane & 15;
  f32x4 acc_u[2], acc_r[2];
  acc_u[0]=(f32x4)0.f; acc_u[1]=(f32x4)0.f; acc_r[0]=(f32x4)0.f; acc_r[1]=(f32x4)0.f;
  #pragma unroll
  for (int ks = 0; ks < 8; ++ks) {
    bf16x8 afr = *(const bf16x8*)&cu_l[fr*CU_S + ks*32 + k8];
    #pragma unroll
    for (int nn = 0; nn < 2; ++nn) {
      int row = wn + nn*16 + fr;
      bf16x8 bu_ = *(const bf16x8*)&WT[(size_t)row*256 + ks*32 + k8];
      bf16x8 br_ = *(const bf16x8*)&WT[32768 + (size_t)row*256 + ks*32 + k8];
      acc_u[nn] = __builtin_amdgcn_mfma_f32_16x16x32_bf16(afr, bu_, acc_u[nn], 0,0,0);
      acc_r[nn] = __builtin_amdgcn_mfma_f32_16x16x32_bf16(afr, br_, acc_r[nn], 0,0,0);
    }
  }
  float u_reg[2][4], hv[2][4];
  float bu4[4], br4[4], bc4[4];
  #pragma unroll
  for (int r = 0; r < 4; ++r) {
    bu4[r] = b_u[n0 + crow + r];
    br4[r] = b_r[n0 + crow + r];
    bc4[r] = b_c[n0 + crow + r];
  }
  #pragma unroll
  for (int nn = 0; nn < 2; ++nn) {
    int col = wn + nn*16 + ccol;
    #pragma unroll
    for (int r = 0; r < 4; ++r) {
      int rown = crow + r;
      float h_ = h_in[((size_t)(b*NNODES)+n0+rown)*HDIM + col];
      hv[nn][r] = h_;
      u_reg[nn][r] = sigmoidf_(bu4[r] + acc_u[nn][r]);
      float rr_ = sigmoidf_(br4[r] + acc_r[nn][r]);
      rh_l[rown*RH_S + col] = f2b(rr_ * h_);
    }
  }
  __syncthreads();
  f32x4 acc_c[2];
  acc_c[0]=(f32x4)0.f; acc_c[1]=(f32x4)0.f;
  #pragma unroll
  for (int ks = 0; ks < 8; ++ks) {
    bf16x8 afr = (ks < 4)
      ? *(const bf16x8*)&cu_l[fr*CU_S + ks*32 + k8]
      : *(const bf16x8*)&rh_l[fr*RH_S + (ks-4)*32 + k8];
    #pragma unroll
    for (int nn = 0; nn < 2; ++nn) {
      int row = wn + nn*16 + fr;
      bf16x8 bc_ = *(const bf16x8*)&WT[65536 + (size_t)row*256 + ks*32 + k8];
      acc_c[nn] = __builtin_amdgcn_mfma_f32_16x16x32_bf16(afr, bc_, acc_c[nn], 0,0,0);
    }
  }
  #pragma unroll
  for (int nn = 0; nn < 2; ++nn) {
    int col = wn + nn*16 + ccol;
    #pragma unroll
    for (int r = 0; r < 4; ++r) {
      int rown = crow + r;
      float cc = tanhf_(bc4[r] + acc_c[nn][r]);
      float u_ = u_reg[nn][r];
      float hp = u_*hv[nn][r] + (1.0f-u_)*cc;
      out[HP_OFF + ((size_t)(b*NNODES)+n0+rown)*HDIM + col] = hp;
      ushort hb = f2b(hp);
      HPB[((size_t)(b*NNODES)+n0+rown)*HDIM + col] = hb;
      hp_l[rown*RH_S + col] = hb;
    }
  }
  __syncthreads();
  #pragma unroll
  for (int k3 = 0; k3 < 3; ++k3) {
    f32x4 acc_t[2];
    acc_t[0]=(f32x4)0.f; acc_t[1]=(f32x4)0.f;
    #pragma unroll
    for (int ks = 0; ks < 4; ++ks) {
      bf16x8 afr = *(const bf16x8*)&hp_l[fr*RH_S + ks*32 + k8];
      #pragma unroll
      for (int nn = 0; nn < 2; ++nn) {
        int row = wn + nn*16 + fr;
        bf16x8 bfr = *(const bf16x8*)&RT[k3*16384 + (size_t)row*128 + ks*32 + k8];
        acc_t[nn] = __builtin_amdgcn_mfma_f32_16x16x32_bf16(afr, bfr, acc_t[nn], 0,0,0);
      }
    }
    #pragma unroll
    for (int nn = 0; nn < 2; ++nn) {
      int col = wn + nn*16 + ccol;
      #pragma unroll
      for (int r = 0; r < 4; ++r)
        TB[((size_t)((b*3+k3)*NNODES)+n0+crow+r)*HDIM + col] = f2b(acc_t[nn][r]);
    }
  }
}

// ---------------- Kernel F: logits via bf16 MFMA, 3 decoders fused -----------
#define LT_S 136
__global__ __launch_bounds__(256) void k_logits_m(
    const float* __restrict__ ws, float* __restrict__ out)
{
  __shared__ ushort t_b[3][64*LT_S];
  __shared__ ushort hp_b[64*LT_S];
  const ushort* TB  = (const ushort*)(ws + WS_T);
  const ushort* HPB = (const ushort*)(ws + HPB_FOFF);
  int tid = threadIdx.x;
  int blk = blockIdx.x;
  int b = blk & 7;
  int rem = blk >> 3;
  int nt = rem >> 4, mt = rem & 15;
  int n0 = nt*64, m0 = mt*64;
  #pragma unroll
  for (int t = 0; t < 4; ++t) {
    int idx = tid + t*256;
    int r = idx >> 4, c = idx & 15;
    *(uint4*)&hp_b[r*LT_S + c*8] =
      *(const uint4*)&HPB[((size_t)(b*NNODES)+m0+r)*HDIM + c*8];
  }
  #pragma unroll
  for (int t = 0; t < 12; ++t) {
    int idx = tid + t*256;
    int k3 = idx >> 10, r = (idx >> 4) & 63, c = idx & 15;
    *(uint4*)&t_b[k3][r*LT_S + c*8] =
      *(const uint4*)&TB[((size_t)((b*3+k3)*NNODES)+n0+r)*HDIM + c*8];
  }
  __syncthreads();
  int w = tid >> 6, lane = tid & 63;
  int nbase = (w >> 1) * 32, mbase = (w & 1) * 32;
  int frow = lane & 15, fk = (lane >> 4) * 8;
  f32x4 acc[3][2][2];
  #pragma unroll
  for (int k3 = 0; k3 < 3; ++k3)
    #pragma unroll
    for (int nn = 0; nn < 2; ++nn)
      #pragma unroll
      for (int mm = 0; mm < 2; ++mm) acc[k3][nn][mm] = (f32x4)0.f;
  #pragma unroll
  for (int ks = 0; ks < 4; ++ks) {
    int ko = ks*32 + fk;
    bf16x8 bfr[2];
    #pragma unroll
    for (int mm = 0; mm < 2; ++mm)
      bfr[mm] = *(const bf16x8*)&hp_b[(mbase + mm*16 + frow)*LT_S + ko];
    #pragma unroll
    for (int k3 = 0; k3 < 3; ++k3)
      #pragma unroll
      for (int nn = 0; nn < 2; ++nn) {
        bf16x8 afr = *(const bf16x8*)&t_b[k3][(nbase + nn*16 + frow)*LT_S + ko];
        #pragma unroll
        for (int mm = 0; mm < 2; ++mm)
          acc[k3][nn][mm] = __builtin_amdgcn_mfma_f32_16x16x32_bf16(
              afr, bfr[mm], acc[k3][nn][mm], 0, 0, 0);
      }
  }
  int crow = (lane >> 4) * 4, ccol = lane & 15;
  #pragma unroll
  for (int nn = 0; nn < 2; ++nn)
    #pragma unroll
    for (int mm = 0; mm < 2; ++mm)
      #pragma unroll
      for (int r = 0; r < 4; ++r) {
        int n = n0 + nbase + nn*16 + crow + r;
        int m = m0 + mbase + mm*16 + ccol;
        float* po = &out[(((size_t)(b*NNODES) + n)*NNODES + m)*3];
        po[0] = acc[0][nn][mm][r];
        po[1] = acc[1][nn][mm][r];
        po[2] = acc[2][nn][mm][r];
      }
}

extern "C" void kernel_launch(void* const* d_in, const int* in_sizes, int n_in,
                              void* d_out, int out_size, void* d_ws, size_t ws_size,
                              hipStream_t stream) {
  (void)in_sizes; (void)n_in; (void)out_size; (void)ws_size;
  const float* x        = (const float*)d_in[0];
  const float* a        = (const float*)d_in[1];
  const float* h        = (const float*)d_in[2];
  const float* Wk       = (const float*)d_in[3];
  const float* att_src  = (const float*)d_in[4];
  const float* att_dst  = (const float*)d_in[5];
  const float* bias_gat = (const float*)d_in[6];
  const float* b_u      = (const float*)d_in[7];
  const float* b_r      = (const float*)d_in[8];
  const float* b_c      = (const float*)d_in[9];
  const float* W_u      = (const float*)d_in[10];
  const float* W_r      = (const float*)d_in[11];
  const float* W_c      = (const float*)d_in[12];
  const float* R_p      = (const float*)d_in[13];
  const float* R_mu     = (const float*)d_in[14];
  const float* R_sg     = (const float*)d_in[15];
  float* out = (float*)d_out;
  float* ws  = (float*)d_ws;

  hipLaunchKernelGGL(k_pre, dim3(274), dim3(256), 0, stream,
                     x, Wk, att_src, att_dst, W_u, W_r, W_c, R_p, R_mu, R_sg, ws, out);
  hipLaunchKernelGGL(k_conv_m, dim3(1024), dim3(256), 0, stream, a, ws, out);
  hipLaunchKernelGGL(k_fuse, dim3(512), dim3(256), 0, stream,
                     h, b_u, b_r, b_c, bias_gat, ws, out);
  hipLaunchKernelGGL(k_logits_m, dim3(2048), dim3(256), 0, stream, ws, out);
}